// Round 14
// baseline (40.856 us; speedup 1.0000x reference)
//
#include <hip/hip_runtime.h>
#include <math.h>

#define B_ 2
#define N_ 20000
#define M_ 1024
#define C_ 256
#define BN_EPS_ 1e-5f

#define NNBLK_PER_B_ 313            // ceil(20000/64), 64 points per NN block
#define GEMM_BLOCKS_ 64             // 8 mt x 2 ot x 4 bh   (128x128 tiles)
#define NN_BLOCKS_   (2 * NNBLK_PER_B_)

// index-carrying sorted top-3 insert, strict < keeps earliest (lowest index).
// Cold merge path only.
#define INSERT3(vv0, vv1, vv2, ii0, ii1, ii2, dd, ss)     \
    {                                                     \
        bool c2_ = (dd) < vv2;                            \
        vv2 = c2_ ? (dd) : vv2;  ii2 = c2_ ? (ss) : ii2;  \
        bool c1_ = vv2 < vv1;                             \
        float tv_ = vv1; int ti_ = ii1;                   \
        vv1 = c1_ ? vv2 : vv1;  ii1 = c1_ ? ii2 : ii1;    \
        vv2 = c1_ ? tv_ : vv2; ii2 = c1_ ? ti_ : ii2;     \
        bool c0_ = vv1 < vv0;                             \
        tv_ = vv0; ti_ = ii0;                             \
        vv0 = c0_ ? vv1 : vv0;  ii0 = c0_ ? ii1 : ii0;    \
        vv1 = c0_ ? tv_ : vv1; ii1 = c0_ ? ti_ : ii1;     \
    }

// slim exact hot-loop insert (R9-proven state-identical to INSERT3)
#define SLIM3(vv0, vv1, vv2, ii0, ii1, ii2, dd, gg)       \
    {                                                     \
        const bool c0_ = (dd) < vv0;                      \
        const bool c1_ = (dd) < vv1;                      \
        const bool c2_ = (dd) < vv2;                      \
        ii2 = c2_ ? (c1_ ? ii1 : (gg)) : ii2;             \
        ii1 = c1_ ? (c0_ ? ii0 : (gg)) : ii1;             \
        ii0 = c0_ ? (gg) : ii0;                           \
        const float nv1_ = __builtin_amdgcn_fmed3f((dd), vv0, vv1); \
        const float nv2_ = __builtin_amdgcn_fmed3f((dd), vv1, vv2); \
        vv0 = fminf((dd), vv0);                           \
        vv1 = nv1_;                                       \
        vv2 = nv2_;                                       \
    }

// ---------------------------------------------------------------------------
// Fused kernel: blocks [0,64) run the head GEMMs (128x128 tile, 8x8/thread)
//               -> part[2 ot][b][5 j][1024 m],
//               blocks [64,690) run 3-NN (R9-verbatim) -> nnres[].
// ---------------------------------------------------------------------------
__global__ __launch_bounds__(256) void k_fused(
    const float* __restrict__ pc, const float* __restrict__ seed,
    const float* __restrict__ feat,
    const float* __restrict__ w1f, const float* __restrict__ b1f,
    const float* __restrict__ g1f, const float* __restrict__ be1f,
    const float* __restrict__ mu1f, const float* __restrict__ var1f,
    const float* __restrict__ w2f, const float* __restrict__ b2f,
    const float* __restrict__ w1c, const float* __restrict__ b1c,
    const float* __restrict__ g1c, const float* __restrict__ be1c,
    const float* __restrict__ mu1c, const float* __restrict__ var1c,
    const float* __restrict__ w2c, const float* __restrict__ b2c,
    float* __restrict__ part, uint4* __restrict__ nnres)
{
    __shared__ float4 smembuf[1584];          // 25344 B, union of both roles
    const int bid = blockIdx.x;
    const int tid = threadIdx.x;

    if (bid < GEMM_BLOCKS_) {
        // =================== GEMM role: 128x128 tile, 8x8 per thread ========
        const int mt = bid & 7;
        const int ot = (bid >> 3) & 1;
        const int bh = bid >> 4;
        const int b = bh >> 1, head = bh & 1;

        const float* __restrict__ w1   = head ? w1c   : w1f;
        const float* __restrict__ b1   = head ? b1c   : b1f;
        const float* __restrict__ g1   = head ? g1c   : g1f;
        const float* __restrict__ be1  = head ? be1c  : be1f;
        const float* __restrict__ mu1  = head ? mu1c  : mu1f;
        const float* __restrict__ var1 = head ? var1c : var1f;
        const float* __restrict__ w2   = head ? w2c   : w2f;
        const float* __restrict__ b2   = head ? b2c   : b2f;
        const int nj = head ? 3 : 2;

        float* base = (float*)smembuf;
        float (*sW)[132]      = (float(*)[132])base;             // 16x132
        float (*sF)[132]      = (float(*)[132])(base + 2112);    // 16x132
        float (*sred)[3][132] = (float(*)[3][132])base;          // overlay post-K

        const int tm = tid & 15;
        const int to = tid >> 4;
        const int m0 = mt * 128, o0 = ot * 128;

        // staging roles: W row so (0..127), c-chunk sc8; F row fc, m-chunk fm
        const int so  = tid >> 1;
        const int sc8 = (tid & 1) << 3;
        const float sscale = g1[o0 + so] * rsqrtf(var1[o0 + so] + BN_EPS_);
        const int fc = tid >> 4;
        const int fm = (tid & 15) << 3;

        const float* __restrict__ wrow = w1 + (size_t)(o0 + so) * C_ + sc8;
        const float* __restrict__ frow = feat + ((size_t)b * C_ + fc) * M_ + m0 + fm;

        float4 wva = *(const float4*)(wrow);
        float4 wvb = *(const float4*)(wrow + 4);
        float4 fva = *(const float4*)(frow);
        float4 fvb = *(const float4*)(frow + 4);

        float acc[2][4][2][4] = {};   // [oh][i][mh][j]

        for (int c0 = 0; c0 < C_; c0 += 16) {
            __syncthreads();
            sW[sc8 + 0][so] = wva.x * sscale;
            sW[sc8 + 1][so] = wva.y * sscale;
            sW[sc8 + 2][so] = wva.z * sscale;
            sW[sc8 + 3][so] = wva.w * sscale;
            sW[sc8 + 4][so] = wvb.x * sscale;
            sW[sc8 + 5][so] = wvb.y * sscale;
            sW[sc8 + 6][so] = wvb.z * sscale;
            sW[sc8 + 7][so] = wvb.w * sscale;
            *(float4*)&sF[fc][fm]     = fva;
            *(float4*)&sF[fc][fm + 4] = fvb;
            __syncthreads();
            const int cn = (c0 + 16 < C_) ? c0 + 16 : c0;
            wva = *(const float4*)(wrow + cn);
            wvb = *(const float4*)(wrow + cn + 4);
            fva = *(const float4*)(frow + (size_t)cn * M_);
            fvb = *(const float4*)(frow + (size_t)cn * M_ + 4);
            #pragma unroll
            for (int cc = 0; cc < 16; ++cc) {
                float4 w0  = *(const float4*)&sW[cc][to << 2];
                float4 w1q = *(const float4*)&sW[cc][64 + (to << 2)];
                float4 f0  = *(const float4*)&sF[cc][tm << 2];
                float4 f1q = *(const float4*)&sF[cc][64 + (tm << 2)];
                const float wr[2][4] = {{w0.x, w0.y, w0.z, w0.w},
                                        {w1q.x, w1q.y, w1q.z, w1q.w}};
                const float fr[2][4] = {{f0.x, f0.y, f0.z, f0.w},
                                        {f1q.x, f1q.y, f1q.z, f1q.w}};
                #pragma unroll
                for (int oh = 0; oh < 2; ++oh)
                    #pragma unroll
                    for (int i = 0; i < 4; ++i)
                        #pragma unroll
                        for (int mh = 0; mh < 2; ++mh)
                            #pragma unroll
                            for (int j = 0; j < 4; ++j)
                                acc[oh][i][mh][j] =
                                    fmaf(wr[oh][i], fr[mh][j], acc[oh][i][mh][j]);
            }
        }

        // relu(bias + acc) in place
        #pragma unroll
        for (int oh = 0; oh < 2; ++oh) {
            #pragma unroll
            for (int i = 0; i < 4; ++i) {
                const int o = o0 + oh * 64 + (to << 2) + i;
                const float sc = g1[o] * rsqrtf(var1[o] + BN_EPS_);
                const float bb = (b1[o] - mu1[o]) * sc + be1[o];
                #pragma unroll
                for (int mh = 0; mh < 2; ++mh)
                    #pragma unroll
                    for (int j = 0; j < 4; ++j)
                        acc[oh][i][mh][j] = fmaxf(acc[oh][i][mh][j] + bb, 0.f);
            }
        }

        __syncthreads();                 // sW/sF dead -> sred overlay safe
        for (int j = 0; j < nj; ++j) {
            float s[2][4] = {};
            #pragma unroll
            for (int oh = 0; oh < 2; ++oh)
                #pragma unroll
                for (int i = 0; i < 4; ++i) {
                    const float w = w2[(size_t)j * C_ + o0 + oh * 64 + (to << 2) + i];
                    #pragma unroll
                    for (int mh = 0; mh < 2; ++mh)
                        #pragma unroll
                        for (int jj = 0; jj < 4; ++jj)
                            s[mh][jj] = fmaf(w, acc[oh][i][mh][jj], s[mh][jj]);
                }
            *(float4*)&sred[to][j][tm << 2]        = *(float4*)s[0];
            *(float4*)&sred[to][j][64 + (tm << 2)] = *(float4*)s[1];
        }
        __syncthreads();

        for (int v = tid; v < nj * 128; v += 256) {
            const int j = v >> 7, m = v & 127;
            float a = 0.f;
            #pragma unroll
            for (int t = 0; t < 16; ++t) a += sred[t][j][m];
            if (ot == 0) a += b2[j];
            const int jg = head ? (2 + j) : j;
            part[(((size_t)ot * B_ + b) * 5 + jg) * M_ + m0 + m] = a;
        }
    } else {
        // =================== NN role (R9 verbatim) ===================
        const int nb = bid - GEMM_BLOCKS_;
        const int b = (nb >= NNBLK_PER_B_) ? 1 : 0;
        const int p0 = (nb - b * NNBLK_PER_B_) << 6;
        const int wv = tid >> 6, lane = tid & 63;

        float4* sseed = smembuf;                                  // 1024 x 16B
        float* nnb = (float*)(smembuf + M_);
        float (*smd)[64][3] = (float(*)[64][3])nnb;               // 4x64x3
        int   (*smi)[64][3] = (int(*)[64][3])(nnb + 768);

        for (int s = tid; s < M_; s += 256) {
            const float kx = seed[((size_t)b * M_ + s) * 3 + 0];
            const float ky = seed[((size_t)b * M_ + s) * 3 + 1];
            const float kz = seed[((size_t)b * M_ + s) * 3 + 2];
            sseed[s] = make_float4(kx, ky, kz, 0.5f * ((kx * kx + ky * ky) + kz * kz));
        }
        __syncthreads();

        const int p = p0 + lane;
        const int pcl = (p < N_) ? p : (N_ - 1);
        const float ux = pc[((size_t)b * N_ + pcl) * 3 + 0];
        const float uy = pc[((size_t)b * N_ + pcl) * 3 + 1];
        const float uz = pc[((size_t)b * N_ + pcl) * 3 + 2];
        const float un = (ux * ux + uy * uy) + uz * uz;

        float v0 = 3.4e38f, v1 = 3.4e38f, v2 = 3.4e38f;
        int i0 = 0, i1 = 0, i2 = 0;
        const int sb = wv << 8;
        const float4* __restrict__ sp = sseed + sb;
        #pragma unroll 8
        for (int t = 0; t < 256; ++t) {
            const float4 k = sp[t];
            // metric = 0.5|k|^2 - u.k  (monotone in d2 = 2*metric + |u|^2)
            const float d = fmaf(-ux, k.x, fmaf(-uy, k.y, fmaf(-uz, k.z, k.w)));
            SLIM3(v0, v1, v2, i0, i1, i2, d, sb + t);
        }

        smd[wv][lane][0] = v0; smd[wv][lane][1] = v1; smd[wv][lane][2] = v2;
        smi[wv][lane][0] = i0; smi[wv][lane][1] = i1; smi[wv][lane][2] = i2;
        __syncthreads();

        if (wv == 0 && p < N_) {
            #pragma unroll
            for (int w = 1; w < 4; ++w) {
                #pragma unroll
                for (int kk = 0; kk < 3; ++kk) {
                    const float dd = smd[w][lane][kk];
                    const int   ss = smi[w][lane][kk];
                    INSERT3(v0, v1, v2, i0, i1, i2, dd, ss);
                }
            }
            const float d0 = sqrtf(fmaxf(fmaf(2.f, v0, un), 1e-12f));
            const float d1 = sqrtf(fmaxf(fmaf(2.f, v1, un), 1e-12f));
            const float d2s = sqrtf(fmaxf(fmaf(2.f, v2, un), 1e-12f));
            const float r0 = 1.f / (d0 + 1e-8f);
            const float r1 = 1.f / (d1 + 1e-8f);
            const float r2 = 1.f / (d2s + 1e-8f);
            const float rs = (r0 + r1) + r2;
            const float q0 = r0 / rs, q1 = r1 / rs, q2 = r2 / rs;
            const unsigned pk =
                (unsigned)i0 | ((unsigned)i1 << 10) | ((unsigned)i2 << 20);
            nnres[(size_t)b * N_ + p] = make_uint4(
                pk, __float_as_uint(q0), __float_as_uint(q1), __float_as_uint(q2));
        }
    }
}

// ---------------------------------------------------------------------------
// Gather epilogue: out[b][j][p] = sum_k q_k * so5[j][idx_k]
// (2 ot-partials now)
// ---------------------------------------------------------------------------
__global__ __launch_bounds__(256) void k_gather(
    const float* __restrict__ part, const uint4* __restrict__ nnres,
    float* __restrict__ out)
{
    const int b = blockIdx.y;
    __shared__ float so5[5][M_];
    for (int v = threadIdx.x; v < 5 * M_; v += 256) {
        const int j = v >> 10, m = v & (M_ - 1);
        const float* __restrict__ pp = part + ((size_t)b * 5 + j) * M_ + m;
        so5[j][m] = pp[0] + pp[10240];
    }
    __syncthreads();

    const int p = (blockIdx.x << 8) + threadIdx.x;
    if (p < N_) {
        const uint4 r = nnres[(size_t)b * N_ + p];
        const int i0 = r.x & 1023, i1 = (r.x >> 10) & 1023, i2 = (r.x >> 20) & 1023;
        const float q0 = __uint_as_float(r.y);
        const float q1 = __uint_as_float(r.z);
        const float q2 = __uint_as_float(r.w);
        #pragma unroll
        for (int j = 0; j < 5; ++j) {
            out[((size_t)b * 5 + j) * N_ + p] =
                fmaf(q0, so5[j][i0], fmaf(q1, so5[j][i1], q2 * so5[j][i2]));
        }
    }
}

// ---------------------------------------------------------------------------
extern "C" void kernel_launch(void* const* d_in, const int* in_sizes, int n_in,
                              void* d_out, int out_size, void* d_ws, size_t ws_size,
                              hipStream_t stream)
{
    const float* pc    = (const float*)d_in[0];
    const float* sxyz  = (const float*)d_in[1];
    const float* feat  = (const float*)d_in[2];
    const float* w1f   = (const float*)d_in[3];
    const float* b1f   = (const float*)d_in[4];
    const float* g1f   = (const float*)d_in[5];
    const float* be1f  = (const float*)d_in[6];
    const float* mu1f  = (const float*)d_in[7];
    const float* var1f = (const float*)d_in[8];
    const float* w2f   = (const float*)d_in[9];
    const float* b2f   = (const float*)d_in[10];
    const float* w1c   = (const float*)d_in[11];
    const float* b1c   = (const float*)d_in[12];
    const float* g1c   = (const float*)d_in[13];
    const float* be1c  = (const float*)d_in[14];
    const float* mu1c  = (const float*)d_in[15];
    const float* var1c = (const float*)d_in[16];
    const float* w2c   = (const float*)d_in[17];
    const float* b2c   = (const float*)d_in[18];

    float* out  = (float*)d_out;
    float* part = (float*)d_ws;                         // 2*2*5*1024 f32 = 80 KB
    uint4* nnres = (uint4*)((char*)d_ws + 163840);      // 40000 * 16 B

    k_fused<<<dim3(GEMM_BLOCKS_ + NN_BLOCKS_), 256, 0, stream>>>(
        pc, sxyz, feat,
        w1f, b1f, g1f, be1f, mu1f, var1f, w2f, b2f,
        w1c, b1c, g1c, be1c, mu1c, var1c, w2c, b2c,
        part, nnres);

    k_gather<<<dim3((N_ + 255) / 256, B_), 256, 0, stream>>>(part, nnres, out);
}